// Round 18
// baseline (128.473 us; speedup 1.0000x reference)
//
#include <hip/hip_runtime.h>

// Problem constants (match reference)
#define BATCHN 32
#define NCELL  4096
#define BN     (BATCHN * NCELL)

// Round 18: R16 (best, 114.2us) + final exact shaves.
//  - BCs behind wave-uniform branches: interior 30/32 blocks skip the two
//    cndmasks via s_cbranch (bcL/bcR were per-lane bools before)
//  - immediate per-step stores (R13 proved == batched), drops b[] staging
// Model (8 variants): per-step wall ~336 device-cyc ~= 78 scalar-VALU ops
// x ~4.3cyc (dep-latency at ILP~1-2); all hiding levers measured <=0
// (R8 TLP, R13 store depth, R17 manual packing). Geometry at constrained
// optimum: CPL=4, OWN=128, HALO=64, KSTEP=60, D=10, 1024 waves = 1/SIMD.
// Pre-commit: if this lands >=110us, declare structural ceiling.
constexpr int OWN    = 128;
constexpr int HALO   = 64;
constexpr int CPL    = 4;                  // cells per lane
constexpr int KSTEP  = 60;                 // steps per launch (< HALO)
constexpr int CHUNKS = NCELL / OWN;        // 32

typedef float v2f __attribute__((ext_vector_type(2)));

// hf = 0.5*f_real(u), hd = 0.5*f_real'(u) (signed; |.| applied at max).
// Horner forms (verified vs reference at u=1: f=1,f'=0; u=0.5:
// f=0.710286, f'=1.085938):
//  hf = u*(0.75 + u*(0.3125 + u*(-13/12 + u*(0.625 - (5/48)u^2))))
//  hd = 0.75 + u*(0.625 + u*(-3.25 + u*(2.5 - 0.625u^2)))
__device__ __forceinline__ void eval2(v2f u, v2f& hf, v2f& hd) {
    v2f u2 = u * u;
    v2f s0 = u2 * (-0.10416666666666667f) + 0.625f;
    v2f s1 = u * s0 + (-1.0833333333333333f);
    v2f s2 = u * s1 + 0.3125f;
    v2f s3 = u * s2 + 0.75f;
    hf = u * s3;
    v2f t0 = u2 * (-0.625f) + 2.5f;
    v2f t1 = u * t0 + (-3.25f);
    v2f t2 = u * t1 + 0.625f;
    hd = u * t2 + 0.75f;
}

__device__ __forceinline__ v2f vmaxabs2(v2f a, v2f b) {
    v2f r;
    r.x = fmaxf(fabsf(a.x), fabsf(b.x));   // |src| modifiers, free
    r.y = fmaxf(fabsf(a.y), fabsf(b.y));
    return r;
}

// lane i <- lane i-1 (edge lane keeps self): DPP WAVE_SHR:1 = 0x138
__device__ __forceinline__ float dpp_left(float v) {
    int i = __float_as_int(v);
    return __int_as_float(
        __builtin_amdgcn_update_dpp(i, i, 0x138, 0xF, 0xF, false));
}
// lane i <- lane i+1 (edge lane keeps self): DPP WAVE_SHL:1 = 0x130
__device__ __forceinline__ float dpp_right(float v) {
    int i = __float_as_int(v);
    return __int_as_float(
        __builtin_amdgcn_update_dpp(i, i, 0x130, 0xF, 0xF, false));
}

// One LF step on 4 cells/lane in even/odd layout E={u0,u2}, O={u1,u3}.
// edgeL/edgeR are WAVE-UNIFORM (chunk==0 / chunk==CHUNKS-1): the BC
// cndmasks sit behind s_cbranch and cost nothing on interior blocks.
__device__ __forceinline__ void lf_step(v2f& E, v2f& O, int lane,
                                        bool edgeL, bool edgeR, float dtdx) {
    v2f hfE, hdE, hfO, hdO;
    eval2(E, hfE, hdE);
    eval2(O, hfO, hdO);

    // exchange: only right neighbor's c0 family (3 DPP)
    float ur  = dpp_right(E.x);
    float hfr = dpp_right(hfE.x);
    float hdr = dpp_right(hdE.x);

    // interfaces i1(c0,c1), i3(c2,c3): fully packed
    v2f F13 = (hfE + hfO) - vmaxabs2(hdE, hdO) * (O - E);
    // interfaces i2(c1,c2), i4(c3, right c0): R-halves {E.y, r}
    v2f Rhf, Ru, Rhd;
    Rhf.x = hfE.y; Rhf.y = hfr;
    Ru.x  = E.y;   Ru.y  = ur;
    Rhd.x = hdE.y; Rhd.y = hdr;
    v2f F24 = (hfO + Rhf) - vmaxabs2(hdO, Rhd) * (Ru - O);

    // left-edge flux = left neighbor's right-edge flux (bit-identical for
    // interior lanes; lane-0 halo garbage firewalled away from owned cells)
    float i0 = dpp_left(F24.y);

    v2f G;
    G.x = i0; G.y = F24.x;
    v2f nE = E - dtdx * (F13 - G);
    v2f nO = O - dtdx * (F24 - F13);

    // outflow BCs: u[0]=u[1], u[N-1]=u[N-2] — uniform branch, then exec mask
    if (edgeL) { if (lane == 16) nE.x = nO.x; }
    if (edgeR) { if (lane == 47) nO.y = nE.y; }

    E = nE;
    O = nO;
}

__global__ __launch_bounds__(64) void lf_wave(const float* __restrict__ in_state,
                                              float* __restrict__ out,
                                              int s0, int nsteps) {
    const int lane  = threadIdx.x;          // one wave per block
    const int wid   = blockIdx.x;
    const int chunk = wid & (CHUNKS - 1);
    const int row   = wid >> 5;             // CHUNKS == 32
    const int gbase = chunk * OWN - HALO;
    const int c0    = lane * CPL;

    const float dtdx = (float)(0.0009 / (10.0 / 4096.0));

    float uin[CPL];
    {
        const float* ip = in_state + (size_t)row * NCELL;
        #pragma unroll
        for (int j = 0; j < CPL; ++j) {
            int g = gbase + c0 + j;
            g = min(max(g, 0), NCELL - 1);
            uin[j] = ip[g];
        }
    }
    v2f E, O;
    E.x = uin[0]; E.y = uin[2];
    O.x = uin[1]; O.y = uin[3];

    // owned cells [64,192) -> lanes 16..47 (all 4 cells contiguous)
    const bool owned = (lane >= 16) && (lane < 48);
    const bool edgeL = (chunk == 0);            // wave-uniform
    const bool edgeR = (chunk == CHUNKS - 1);   // wave-uniform

    float* op = out + (size_t)(s0 + 1) * BN + (size_t)row * NCELL + (gbase + c0);

    // dispatch 0: write plane 0 (= init), replacing the d2d memcpy
    if (s0 == 0 && owned) {
        *(float4*)(op - BN) = make_float4(uin[0], uin[1], uin[2], uin[3]);
    }

    #pragma unroll 4
    for (int t = 0; t < nsteps; ++t) {
        lf_step(E, O, lane, edgeL, edgeR, dtdx);
        if (owned) {
            *(float4*)op = make_float4(E.x, O.x, E.y, O.y);
        }
        op += BN;
    }
}

extern "C" void kernel_launch(void* const* d_in, const int* in_sizes, int n_in,
                              void* d_out, int out_size, void* d_ws, size_t ws_size,
                              hipStream_t stream) {
    const float* init = (const float*)d_in[0];
    float* out = (float*)d_out;

    const int total = out_size / BN - 1;

    const int nblocks = CHUNKS * BATCHN;    // 1024 waves, 1/SIMD chip-wide
    for (int s = 0; s < total; s += KSTEP) {
        int ns = (total - s) < KSTEP ? (total - s) : KSTEP;
        const float* src = (s == 0) ? init : out + (size_t)s * BN;
        lf_wave<<<nblocks, 64, 0, stream>>>(src, out, s, ns);
    }
}

// Round 19
// 113.924 us; speedup vs baseline: 1.1277x; 1.1277x over previous
//
#include <hip/hip_runtime.h>

// Problem constants (match reference)
#define BATCHN 32
#define NCELL  4096
#define BN     (BATCHN * NCELL)

// Round 19: revert to R16 verbatim — the measured optimum (114.2 us).
// R18's "shaves" both regressed: per-step stores directly from E/O
// recreate a store-source-register hazard (E/O rewritten next step ->
// vmcnt/copy), and the per-step s_cbranch pair costs scalar-issue slots.
// R16's 4-deep b[] rotation decouples store data from live state for free.
//
// Final model (9 falsification rounds): dur = 600 steps x ~45 v2f-ops
// x ~4.3 cyc/scalar-equiv (dependency-issue floor at 1 wave/SIMD; TLP,
// store-depth, DS->DPP, persistent-kernel, manual VOP3P all measured <=0)
// + 10 x ~3us dispatch OH. Geometry at constrained optimum: CPL=4,
// OWN=128, HALO=64, KSTEP=60, D=10, 1024 waves = 1/SIMD.
constexpr int OWN    = 128;
constexpr int HALO   = 64;
constexpr int CPL    = 4;                  // cells per lane
constexpr int KSTEP  = 60;                 // steps per launch (< HALO)
constexpr int CHUNKS = NCELL / OWN;        // 32

typedef float v2f __attribute__((ext_vector_type(2)));

// hf = 0.5*f_real(u), hd = 0.5*f_real'(u) (signed; |.| applied at max).
// Horner forms (coefficients verified vs reference at u=1: f=1,f'=0 and
// u=0.5: f=0.710286, f'=1.085938):
//  hf = u*(0.75 + u*(0.3125 + u*(-13/12 + u*(0.625 - (5/48)u^2))))
//  hd = 0.75 + u*(0.625 + u*(-3.25 + u*(2.5 - 0.625u^2)))
__device__ __forceinline__ void eval2(v2f u, v2f& hf, v2f& hd) {
    v2f u2 = u * u;
    v2f s0 = u2 * (-0.10416666666666667f) + 0.625f;
    v2f s1 = u * s0 + (-1.0833333333333333f);
    v2f s2 = u * s1 + 0.3125f;
    v2f s3 = u * s2 + 0.75f;
    hf = u * s3;
    v2f t0 = u2 * (-0.625f) + 2.5f;
    v2f t1 = u * t0 + (-3.25f);
    v2f t2 = u * t1 + 0.625f;
    hd = u * t2 + 0.75f;
}

__device__ __forceinline__ v2f vmaxabs2(v2f a, v2f b) {
    v2f r;
    r.x = fmaxf(fabsf(a.x), fabsf(b.x));   // |src| modifiers, free in VOP3
    r.y = fmaxf(fabsf(a.y), fabsf(b.y));
    return r;
}

// lane i <- lane i-1 (edge lane keeps self): DPP WAVE_SHR:1 = 0x138
__device__ __forceinline__ float dpp_left(float v) {
    int i = __float_as_int(v);
    return __int_as_float(
        __builtin_amdgcn_update_dpp(i, i, 0x138, 0xF, 0xF, false));
}
// lane i <- lane i+1 (edge lane keeps self): DPP WAVE_SHL:1 = 0x130
__device__ __forceinline__ float dpp_right(float v) {
    int i = __float_as_int(v);
    return __int_as_float(
        __builtin_amdgcn_update_dpp(i, i, 0x130, 0xF, 0xF, false));
}

// One LF step on 4 cells/lane in even/odd layout E={u0,u2}, O={u1,u3}.
__device__ __forceinline__ void lf_step(v2f& E, v2f& O, float b[CPL],
                                        bool bcL, bool bcR, float dtdx) {
    v2f hfE, hdE, hfO, hdO;
    eval2(E, hfE, hdE);
    eval2(O, hfO, hdO);

    // exchange: only right neighbor's c0 family (3 DPP)
    float ur  = dpp_right(E.x);
    float hfr = dpp_right(hfE.x);
    float hdr = dpp_right(hdE.x);

    // interfaces i1(c0,c1), i3(c2,c3): fully packed
    v2f F13 = (hfE + hfO) - vmaxabs2(hdE, hdO) * (O - E);
    // interfaces i2(c1,c2), i4(c3, right c0): R-halves {E.y, r}
    v2f Rhf, Ru, Rhd;
    Rhf.x = hfE.y; Rhf.y = hfr;
    Ru.x  = E.y;   Ru.y  = ur;
    Rhd.x = hdE.y; Rhd.y = hdr;
    v2f F24 = (hfO + Rhf) - vmaxabs2(hdO, Rhd) * (Ru - O);

    // left-edge flux = left neighbor's right-edge flux (bit-identical to
    // computing it from exchanged left values; lane 0 garbage firewalled)
    float i0 = dpp_left(F24.y);

    v2f G;
    G.x = i0; G.y = F24.x;
    v2f nE = E - dtdx * (F13 - G);
    v2f nO = O - dtdx * (F24 - F13);

    // outflow BCs: u[0]=u[1] (cell0 <- cell1), u[N-1]=u[N-2] (cell3 <- cell2)
    if (bcL) nE.x = nO.x;
    if (bcR) nO.y = nE.y;

    b[0] = nE.x; b[1] = nO.x; b[2] = nE.y; b[3] = nO.y;
    E = nE;
    O = nO;
}

__global__ __launch_bounds__(64) void lf_wave(const float* __restrict__ in_state,
                                              float* __restrict__ out,
                                              int s0, int nsteps) {
    const int lane  = threadIdx.x;          // one wave per block
    const int wid   = blockIdx.x;
    const int chunk = wid & (CHUNKS - 1);
    const int row   = wid >> 5;             // CHUNKS == 32
    const int gbase = chunk * OWN - HALO;
    const int c0    = lane * CPL;

    const float dtdx = (float)(0.0009 / (10.0 / 4096.0));

    float uin[CPL];
    {
        const float* ip = in_state + (size_t)row * NCELL;
        #pragma unroll
        for (int j = 0; j < CPL; ++j) {
            int g = gbase + c0 + j;
            g = min(max(g, 0), NCELL - 1);
            uin[j] = ip[g];
        }
    }
    v2f E, O;
    E.x = uin[0]; E.y = uin[2];
    O.x = uin[1]; O.y = uin[3];

    // owned cells [64,192) -> lanes 16..47 (all 4 cells contiguous)
    const bool owned = (lane >= 16) && (lane < 48);
    const bool bcL = (chunk == 0) && (lane == 16);            // global cell 0
    const bool bcR = (chunk == CHUNKS - 1) && (lane == 47);   // global cell N-1

    float* op = out + (size_t)(s0 + 1) * BN + (size_t)row * NCELL + (gbase + c0);

    // dispatch 0: write plane 0 (= init), replacing the d2d memcpy
    if (s0 == 0 && owned) {
        *(float4*)(op - BN) = make_float4(uin[0], uin[1], uin[2], uin[3]);
    }

    int t = 0;
    // groups of 4 steps, stores batched per group in one exec region
    for (; t + 4 <= nsteps; t += 4) {
        float b0[CPL], b1[CPL], b2[CPL], b3[CPL];
        lf_step(E, O, b0, bcL, bcR, dtdx);
        lf_step(E, O, b1, bcL, bcR, dtdx);
        lf_step(E, O, b2, bcL, bcR, dtdx);
        lf_step(E, O, b3, bcL, bcR, dtdx);
        if (owned) {
            *(float4*)(op)            = make_float4(b0[0], b0[1], b0[2], b0[3]);
            *(float4*)(op + BN)       = make_float4(b1[0], b1[1], b1[2], b1[3]);
            *(float4*)(op + 2 * BN)   = make_float4(b2[0], b2[1], b2[2], b2[3]);
            *(float4*)(op + 3 * BN)   = make_float4(b3[0], b3[1], b3[2], b3[3]);
        }
        op += 4 * BN;
    }
    // tail (not hit for nsteps=60, kept for robustness)
    for (; t < nsteps; ++t) {
        float b[CPL];
        lf_step(E, O, b, bcL, bcR, dtdx);
        if (owned) *(float4*)op = make_float4(b[0], b[1], b[2], b[3]);
        op += BN;
    }
}

extern "C" void kernel_launch(void* const* d_in, const int* in_sizes, int n_in,
                              void* d_out, int out_size, void* d_ws, size_t ws_size,
                              hipStream_t stream) {
    const float* init = (const float*)d_in[0];
    float* out = (float*)d_out;

    const int total = out_size / BN - 1;

    const int nblocks = CHUNKS * BATCHN;    // 1024 waves, 1/SIMD chip-wide
    for (int s = 0; s < total; s += KSTEP) {
        int ns = (total - s) < KSTEP ? (total - s) : KSTEP;
        const float* src = (s == 0) ? init : out + (size_t)s * BN;
        lf_wave<<<nblocks, 64, 0, stream>>>(src, out, s, ns);
    }
}